// Round 1
// baseline (274.244 us; speedup 1.0000x reference)
//
#include <hip/hip_runtime.h>
#include <hip/hip_bf16.h>
#include <math.h>

// Problem constants (OptimizeSNR): x[B,C,L] fp32, kernel length K, 'same' pad.
constexpr int Bc = 8;
constexpr int Cc = 128;
constexpr int Lc = 32768;
constexpr int Kc = 129;
constexpr int PAD = Kc / 2;        // 64
constexpr int HALO = Kc - 1;       // 128

constexpr int THREADS = 256;
constexpr int R = 8;               // consecutive outputs per thread
constexpr int TILE = THREADS * R;  // 2048 outputs per block
constexpr int LXN = TILE + HALO + R; // staged floats (incl. shift overrun slack) = 2184

__device__ __forceinline__ int swz(int i) {
    // XOR-swizzle: inject bits [7:5] into [2:0] so stride-8 reads hit 32 banks.
    return i ^ ((i >> 5) & 7);
}

// Per-channel complex scale: sc = nm*cos(atan(a)), ss = nm*sin(atan(a))
__global__ void scale_kernel(const float* __restrict__ wm,
                             const float* __restrict__ wa,
                             float* __restrict__ ws, int C, float batchf) {
    int c = threadIdx.x;
    if (c >= C) return;
    float m = -1e30f;
    for (int i = 0; i < C; ++i) m = fmaxf(m, wm[i]);
    float s = 0.f;
    for (int i = 0; i < C; ++i) s += expf(wm[i] - m);
    float e = expf(wm[c] - m);
    float nm = batchf * e / s;           // batch * softmax
    float a = wa[c];
    float inv = rsqrtf(1.f + a * a);     // cos(atan(a))
    ws[2 * c]     = nm * inv;            // sc
    ws[2 * c + 1] = nm * a * inv;        // ss
}

__global__ __launch_bounds__(THREADS)
void mf_kernel(const float* __restrict__ x,
               const float* __restrict__ kr,
               const float* __restrict__ ki,
               const float* __restrict__ sc_ss,
               float* __restrict__ out, int interleaved) {
    __shared__ float lx[LXN];

    const int tile = blockIdx.x;          // tile within row
    const int row  = blockIdx.y;          // b*C + c
    const int c    = row & (Cc - 1);
    const float* __restrict__ xrow = x + (size_t)row * Lc;
    const int t0 = tile * TILE;

    // Stage x[t0-PAD .. t0-PAD+LXN) with zero padding at row edges.
    for (int i = threadIdx.x; i < LXN; i += THREADS) {
        int g = t0 - PAD + i;
        float v = (g >= 0 && g < Lc) ? xrow[g] : 0.f;
        lx[swz(i)] = v;
    }
    __syncthreads();

    const float sc = sc_ss[2 * c];
    const float ss = sc_ss[2 * c + 1];

    const int base = threadIdx.x * R;

    float accr[R], acci[R], w[R];
    #pragma unroll
    for (int j = 0; j < R; ++j) { accr[j] = 0.f; acci[j] = 0.f; }
    #pragma unroll
    for (int j = 0; j < R; ++j) w[j] = lx[swz(base + j)];

    for (int t = 0; t < Kc; ++t) {
        const float vr = kr[t];   // wave-uniform -> s_load
        const float vi = ki[t];
        #pragma unroll
        for (int j = 0; j < R; ++j) {
            accr[j] = fmaf(w[j], vr, accr[j]);
            acci[j] = fmaf(w[j], vi, acci[j]);
        }
        // shift window by one sample
        float nw = lx[swz(base + t + R)];
        #pragma unroll
        for (int j = 0; j < R - 1; ++j) w[j] = w[j + 1];
        w[R - 1] = nw;
    }

    // y = accr - i*acci (conj kernel); out = (sc - i*ss) * y
    float re[R], im[R];
    #pragma unroll
    for (int j = 0; j < R; ++j) {
        re[j] = sc * accr[j] - ss * acci[j];
        im[j] = -sc * acci[j] - ss * accr[j];
    }

    const size_t orow = (size_t)row * Lc + t0 + base;
    if (!interleaved) {
        float4* o4 = reinterpret_cast<float4*>(out + orow);
        o4[0] = make_float4(re[0], re[1], re[2], re[3]);
        o4[1] = make_float4(re[4], re[5], re[6], re[7]);
    } else {
        float2* o2 = reinterpret_cast<float2*>(out) + orow;
        #pragma unroll
        for (int j = 0; j < R; ++j) o2[j] = make_float2(re[j], im[j]);
    }
}

extern "C" void kernel_launch(void* const* d_in, const int* in_sizes, int n_in,
                              void* d_out, int out_size, void* d_ws, size_t ws_size,
                              hipStream_t stream) {
    const float* x  = (const float*)d_in[0];
    const float* wm = (const float*)d_in[1];
    const float* wa = (const float*)d_in[2];
    const float* kr = (const float*)d_in[3];
    const float* ki = (const float*)d_in[4];
    float* out = (float*)d_out;
    float* ws  = (float*)d_ws;

    const int C = in_sizes[1];  // 128
    const long long N = (long long)Bc * Cc * Lc;
    const int interleaved = (out_size == 2 * N) ? 1 : 0;

    hipLaunchKernelGGL(scale_kernel, dim3(1), dim3(C), 0, stream,
                       wm, wa, ws, C, (float)Bc);

    dim3 grid(Lc / TILE, Bc * Cc);
    hipLaunchKernelGGL(mf_kernel, grid, dim3(THREADS), 0, stream,
                       x, kr, ki, ws, out, interleaved);
}

// Round 2
// 187.649 us; speedup vs baseline: 1.4615x; 1.4615x over previous
//
#include <hip/hip_runtime.h>
#include <hip/hip_bf16.h>
#include <math.h>

// OptimizeSNR: matched filter (cross-corr with conj complex kernel, 'same' pad)
// + per-channel complex scale; output = real part (out_size == B*C*L).
constexpr int Bc = 8;
constexpr int Cc = 128;
constexpr int Lc = 32768;
constexpr int Kc = 129;
constexpr int PAD = Kc / 2;        // 64

constexpr int THREADS = 256;
constexpr int R = 16;              // consecutive outputs per thread
constexpr int W = 32;              // circular register window (floats), W >= R+4, 129 = 4*W + 1
constexpr int TILE = THREADS * R;  // 4096 outputs per block
// staged floats: max read index = base_max + 159 = 255*16 + 159 = 4239
constexpr int LXN = 4240;

// Per-channel complex scale: sc = nm*cos(atan(a)), ss = nm*sin(atan(a))
__global__ void scale_kernel(const float* __restrict__ wm,
                             const float* __restrict__ wa,
                             float* __restrict__ ws, int C, float batchf) {
    int c = threadIdx.x;
    if (c >= C) return;
    float m = -1e30f;
    for (int i = 0; i < C; ++i) m = fmaxf(m, wm[i]);
    float s = 0.f;
    for (int i = 0; i < C; ++i) s += expf(wm[i] - m);
    float e = expf(wm[c] - m);
    float nm = batchf * e / s;           // batch * softmax
    float a = wa[c];
    float inv = rsqrtf(1.f + a * a);     // cos(atan(a))
    ws[2 * c]     = nm * inv;            // sc
    ws[2 * c + 1] = nm * a * inv;        // ss
}

__global__ __launch_bounds__(THREADS)
void mf_kernel(const float* __restrict__ x,
               const float* __restrict__ kr,
               const float* __restrict__ ki,
               const float* __restrict__ sc_ss,
               float* __restrict__ out, int interleaved) {
    __shared__ float lx[LXN];

    const int tile = blockIdx.x;          // tile within row
    const int row  = blockIdx.y;          // b*C + c
    const int c    = row & (Cc - 1);
    const float* __restrict__ xrow = x + (size_t)row * Lc;
    const int t0 = tile * TILE;

    // Stage x[t0-PAD .. t0-PAD+LXN) with zero padding at row edges (float4).
    for (int i = 4 * threadIdx.x; i < LXN; i += 4 * THREADS) {
        int g = t0 - PAD + i;
        float4 v;
        if (g >= 0 && g + 3 < Lc) {
            v = *reinterpret_cast<const float4*>(xrow + g);
        } else {
            v.x = (g + 0 >= 0 && g + 0 < Lc) ? xrow[g + 0] : 0.f;
            v.y = (g + 1 >= 0 && g + 1 < Lc) ? xrow[g + 1] : 0.f;
            v.z = (g + 2 >= 0 && g + 2 < Lc) ? xrow[g + 2] : 0.f;
            v.w = (g + 3 >= 0 && g + 3 < Lc) ? xrow[g + 3] : 0.f;
        }
        *reinterpret_cast<float4*>(&lx[i]) = v;
    }
    __syncthreads();

    const float sc = sc_ss[2 * c];
    const float ss = sc_ss[2 * c + 1];

    const int base = threadIdx.x * R;

    float accr[R], acci[R];
    #pragma unroll
    for (int j = 0; j < R; ++j) { accr[j] = 0.f; acci[j] = 0.f; }

    // Init circular window w[0..31] = x[base .. base+31]
    float w[W];
    #pragma unroll
    for (int s = 0; s < W / 4; ++s) {
        float4 v = *reinterpret_cast<const float4*>(&lx[base + 4 * s]);
        w[4 * s + 0] = v.x; w[4 * s + 1] = v.y; w[4 * s + 2] = v.z; w[4 * s + 3] = v.w;
    }

    // 4 bodies of W=32 taps each (128 taps), then tap 128.
    #pragma unroll 1
    for (int body = 0; body < 4; ++body) {
        const int tb = body * W;
        // Tap coefficients: uniform loads -> scalar pipe
        float vr[W], vi[W];
        #pragma unroll
        for (int u = 0; u < W; ++u) { vr[u] = kr[tb + u]; vi[u] = ki[tb + u]; }

        #pragma unroll
        for (int s = 0; s < W / 4; ++s) {
            #pragma unroll
            for (int q = 0; q < 4; ++q) {
                const int u = 4 * s + q;
                #pragma unroll
                for (int j = 0; j < R; ++j) {
                    const float xv = w[(u + j) & (W - 1)];
                    accr[j] = fmaf(xv, vr[u], accr[j]);
                    acci[j] = fmaf(xv, vi[u], acci[j]);
                }
            }
            // slots 4s..4s+3 now dead; prefetch x[base + tb + W + 4s .. +3]
            float4 p = *reinterpret_cast<const float4*>(&lx[base + tb + W + 4 * s]);
            w[4 * s + 0] = p.x; w[4 * s + 1] = p.y; w[4 * s + 2] = p.z; w[4 * s + 3] = p.w;
        }
    }
    // Tap 128: window now holds x[base+128 .. base+159] at slots 0..31.
    {
        const float vr = kr[Kc - 1];
        const float vi = ki[Kc - 1];
        #pragma unroll
        for (int j = 0; j < R; ++j) {
            const float xv = w[j];
            accr[j] = fmaf(xv, vr, accr[j]);
            acci[j] = fmaf(xv, vi, acci[j]);
        }
    }

    // y = accr - i*acci (conj kernel); out = (sc - i*ss) * y
    const size_t orow = (size_t)row * Lc + t0 + base;
    if (!interleaved) {
        float4* o4 = reinterpret_cast<float4*>(out + orow);
        #pragma unroll
        for (int s = 0; s < R / 4; ++s) {
            float4 v;
            v.x = sc * accr[4 * s + 0] - ss * acci[4 * s + 0];
            v.y = sc * accr[4 * s + 1] - ss * acci[4 * s + 1];
            v.z = sc * accr[4 * s + 2] - ss * acci[4 * s + 2];
            v.w = sc * accr[4 * s + 3] - ss * acci[4 * s + 3];
            o4[s] = v;
        }
    } else {
        float2* o2 = reinterpret_cast<float2*>(out) + orow;
        #pragma unroll
        for (int j = 0; j < R; ++j) {
            float re = sc * accr[j] - ss * acci[j];
            float im = -sc * acci[j] - ss * accr[j];
            o2[j] = make_float2(re, im);
        }
    }
}

extern "C" void kernel_launch(void* const* d_in, const int* in_sizes, int n_in,
                              void* d_out, int out_size, void* d_ws, size_t ws_size,
                              hipStream_t stream) {
    const float* x  = (const float*)d_in[0];
    const float* wm = (const float*)d_in[1];
    const float* wa = (const float*)d_in[2];
    const float* kr = (const float*)d_in[3];
    const float* ki = (const float*)d_in[4];
    float* out = (float*)d_out;
    float* ws  = (float*)d_ws;

    const int C = in_sizes[1];  // 128
    const long long N = (long long)Bc * Cc * Lc;
    const int interleaved = (out_size == 2 * N) ? 1 : 0;

    hipLaunchKernelGGL(scale_kernel, dim3(1), dim3(C), 0, stream,
                       wm, wa, ws, C, (float)Bc);

    dim3 grid(Lc / TILE, Bc * Cc);
    hipLaunchKernelGGL(mf_kernel, grid, dim3(THREADS), 0, stream,
                       x, kr, ki, ws, out, interleaved);
}

// Round 3
// 83.325 us; speedup vs baseline: 3.2912x; 2.2520x over previous
//
#include <hip/hip_runtime.h>
#include <hip/hip_bf16.h>
#include <math.h>

// OptimizeSNR via MFMA: out[n, t+m] = sum_p A[m,p] * B[p,n]
//   A[m,p] = k[p-m]  (16x160 kernel Toeplitz, 5 frags/filter, in VGPRs)
//   B[p,n] = x_rowN[s0+p]  (bf16 in LDS, 16 rows per block)
constexpr int Bc = 8, Cc = 128, Lc = 32768, Kc = 129, PAD = Kc / 2;

constexpr int ROWS   = 16;            // channel-rows per block (MFMA N dim)
constexpr int MLEN   = 1024;          // output positions per block per row
constexpr int PSPAN  = MLEN + 144;    // staged positions (incl. 144 halo)
constexpr int PSTR   = 1176;          // padded row stride; PSTR/8=147 odd -> 2-way-free frag reads
constexpr int THREADS= 512;
constexpr int NTILES = MLEN / 16;     // 64 tiles of 16 outputs
constexpr int NWAVES = THREADS / 64;  // 8
constexpr int TPW    = NTILES / NWAVES; // 8 tiles per wave

typedef __attribute__((ext_vector_type(8))) short short8;
typedef __attribute__((ext_vector_type(4))) float floatx4;

__device__ __forceinline__ unsigned short f2bf(float f) {
    unsigned u = __builtin_bit_cast(unsigned, f);
    u += 0x7fffu + ((u >> 16) & 1u);   // RNE
    return (unsigned short)(u >> 16);
}

// Per-channel complex scale: sc = nm*cos(atan(a)), ss = nm*sin(atan(a))
__global__ void scale_kernel(const float* __restrict__ wm,
                             const float* __restrict__ wa,
                             float* __restrict__ ws, int C, float batchf) {
    int c = threadIdx.x;
    if (c >= C) return;
    float m = -1e30f;
    for (int i = 0; i < C; ++i) m = fmaxf(m, wm[i]);
    float s = 0.f;
    for (int i = 0; i < C; ++i) s += expf(wm[i] - m);
    float nm = batchf * expf(wm[c] - m) / s;
    float a = wa[c];
    float inv = rsqrtf(1.f + a * a);
    ws[2 * c]     = nm * inv;       // sc
    ws[2 * c + 1] = nm * a * inv;   // ss
}

__global__ __launch_bounds__(THREADS)
void mf_kernel(const float* __restrict__ x,
               const float* __restrict__ kr,
               const float* __restrict__ ki,
               const float* __restrict__ sc_ss,
               float* __restrict__ out, int interleaved) {
    __shared__ __align__(16) unsigned short lx[ROWS * PSTR];

    const int bx   = blockIdx.x;       // position tile
    const int bg   = blockIdx.y;       // row group (16 rows)
    const int row0 = bg * ROWS;
    const int P0   = bx * MLEN;
    const int s0   = P0 - PAD;

    const int tid  = threadIdx.x;
    const int lane = tid & 63;
    const int fh   = lane >> 4;        // 0..3
    const int fn   = lane & 15;        // 0..15

    // ---- A fragments: A_d[m][kl] = k[32d + kl - m]; lane holds m=fn, kl=8*fh+e ----
    short8 ar[5], ai[5];
    #pragma unroll
    for (int d = 0; d < 5; ++d) {
        #pragma unroll
        for (int e = 0; e < 8; ++e) {
            int idx = 32 * d + 8 * fh + e - fn;
            bool ok = (idx >= 0) && (idx < Kc);
            ar[d][e] = (short)f2bf(ok ? kr[idx] : 0.f);
            ai[d][e] = (short)f2bf(ok ? ki[idx] : 0.f);
        }
    }

    // ---- stage x[row0..row0+15][s0 .. s0+PSPAN) as bf16 into LDS ----
    const int srow = tid >> 5;         // 32 threads per row
    const int scol = tid & 31;
    const float* __restrict__ xr = x + (size_t)(row0 + srow) * Lc;
    unsigned short* lrow = &lx[srow * PSTR];
    const bool interior = (s0 >= 0) && (s0 + PSPAN <= Lc);
    for (int i4 = scol; i4 < PSPAN / 4; i4 += 32) {
        int g = s0 + 4 * i4;
        float4 v;
        if (interior) {
            v = *reinterpret_cast<const float4*>(xr + g);
        } else {
            v.x = (g + 0 >= 0 && g + 0 < Lc) ? xr[g + 0] : 0.f;
            v.y = (g + 1 >= 0 && g + 1 < Lc) ? xr[g + 1] : 0.f;
            v.z = (g + 2 >= 0 && g + 2 < Lc) ? xr[g + 2] : 0.f;
            v.w = (g + 3 >= 0 && g + 3 < Lc) ? xr[g + 3] : 0.f;
        }
        ushort4 h;
        h.x = f2bf(v.x); h.y = f2bf(v.y); h.z = f2bf(v.z); h.w = f2bf(v.w);
        *reinterpret_cast<ushort4*>(&lrow[4 * i4]) = h;
    }
    __syncthreads();

    // ---- per-lane channel scale (lane owns channel-row row0+fn) ----
    const int ch = (row0 + fn) & (Cc - 1);
    const float scv = sc_ss[2 * ch];
    const float ssv = sc_ss[2 * ch + 1];
    const int wv = tid >> 6;

    for (int jj = 0; jj < TPW; ++jj) {
        const int j  = wv * TPW + jj;
        const int pb = 16 * j;
        // B frag: lane holds B[kl=8*fh+e][n=fn] = x_row(fn)[s0 + pb + 32d + 8*fh + e]
        const unsigned short* lp = &lx[fn * PSTR + pb + 8 * fh];
        floatx4 cr = {0.f, 0.f, 0.f, 0.f};
        floatx4 cim = {0.f, 0.f, 0.f, 0.f};
        #pragma unroll
        for (int d = 0; d < 5; ++d) {
            short8 b = *reinterpret_cast<const short8*>(lp + 32 * d);
            cr  = __builtin_amdgcn_mfma_f32_16x16x32_bf16(ar[d], b, cr, 0, 0, 0);
            cim = __builtin_amdgcn_mfma_f32_16x16x32_bf16(ai[d], b, cim, 0, 0, 0);
        }
        // D layout: lane holds D[m = 4*fh + r][n = fn]
        const size_t obase = (size_t)(row0 + fn) * Lc + P0 + pb + 4 * fh;
        if (!interleaved) {
            float4 o;
            o.x = scv * cr[0] - ssv * cim[0];
            o.y = scv * cr[1] - ssv * cim[1];
            o.z = scv * cr[2] - ssv * cim[2];
            o.w = scv * cr[3] - ssv * cim[3];
            *reinterpret_cast<float4*>(out + obase) = o;
        } else {
            float2* o2 = reinterpret_cast<float2*>(out) + obase;
            #pragma unroll
            for (int r = 0; r < 4; ++r) {
                o2[r] = make_float2(scv * cr[r] - ssv * cim[r],
                                    -scv * cim[r] - ssv * cr[r]);
            }
        }
    }
}

extern "C" void kernel_launch(void* const* d_in, const int* in_sizes, int n_in,
                              void* d_out, int out_size, void* d_ws, size_t ws_size,
                              hipStream_t stream) {
    const float* x  = (const float*)d_in[0];
    const float* wm = (const float*)d_in[1];
    const float* wa = (const float*)d_in[2];
    const float* kr = (const float*)d_in[3];
    const float* ki = (const float*)d_in[4];
    float* out = (float*)d_out;
    float* ws  = (float*)d_ws;

    const int C = in_sizes[1];  // 128
    const long long N = (long long)Bc * Cc * Lc;
    const int interleaved = (out_size == 2 * N) ? 1 : 0;

    hipLaunchKernelGGL(scale_kernel, dim3(1), dim3(C), 0, stream,
                       wm, wa, ws, C, (float)Bc);

    dim3 grid(Lc / MLEN, (Bc * Cc) / ROWS);   // 32 x 64
    hipLaunchKernelGGL(mf_kernel, grid, dim3(THREADS), 0, stream,
                       x, kr, ki, ws, out, interleaved);
}